// Round 5
// baseline (208.441 us; speedup 1.0000x reference)
//
#include <hip/hip_runtime.h>
#include <math.h>

#define V 32768
#define D 15
#define DM 1024
#define B 8
#define T 1024
#define NNODES (V - 1)  // 32767
#define R 4             // rows per pass per wave; 2 passes -> 8 rows/wave, 32/block

// Kernel 1: sig[v*B + b] = sigmoid(dot(W[v], x[b]) + bias[v]) for all internal nodes.
// Grid 1024 x 256 threads (4 waves). Each wave: 2 passes of R=4 rows, K split across
// 64 lanes (4 float4 per lane per row).
//
// R4 post-mortem: the R4 kernel was latency-bound (4 iters of issue-4-loads ->
// vmcnt(0) -> compute, ~900cyc HBM latency exposed each iter). This version:
//  - software-pipelines W loads one iteration ahead (wvn prefetch),
//  - runs 2 passes per wave so pass-0's fold/store epilogue hides pass-1's
//    first-load latency,
//  - readfirstlane's the wave id so row addressing/clamps are scalar (SGPR).
// R3 lesson preserved: all acc[] indices are compile-time constants (no scratch).
__global__ __launch_bounds__(256, 4) void hsm_logits_kernel(
    const float* __restrict__ x,     // [B][DM]
    const float* __restrict__ W,     // [NNODES][DM]
    const float* __restrict__ bias,  // [NNODES]
    float* __restrict__ sig)         // [NNODES][B]
{
    __shared__ float4 xs[B * DM / 4];  // 32 KB, xs[b*256 + u]

    const float4* x4 = (const float4*)x;
    #pragma unroll
    for (int i = threadIdx.x; i < B * DM / 4; i += 256) xs[i] = x4[i];
    __syncthreads();

    const int wave = __builtin_amdgcn_readfirstlane(threadIdx.x >> 6);  // scalarize
    const int lane = threadIdx.x & 63;
    const int rowbase = blockIdx.x * 32 + wave * 8;

    const float4* Wb = (const float4*)W;

    float4 wv[R], wvn[R];
    float acc[R * B];  // acc[r*8+b]

    // Preload pass-0, j=0.
    #pragma unroll
    for (int r = 0; r < R; r++) {
        int row = rowbase + r;
        if (row > NNODES - 1) row = NNODES - 1;  // scalar clamp; store guarded below
        wv[r] = Wb[(size_t)row * 256 + lane];
    }

    auto run_pass = [&](int prow0, bool preload_next, int nrow0) {
        #pragma unroll
        for (int i = 0; i < R * B; i++) acc[i] = 0.f;
        #pragma unroll
        for (int j = 0; j < 4; j++) {
            if (j < 3) {
                #pragma unroll
                for (int r = 0; r < R; r++) {
                    int row = prow0 + r;
                    if (row > NNODES - 1) row = NNODES - 1;
                    wvn[r] = Wb[(size_t)row * 256 + (j + 1) * 64 + lane];
                }
            } else if (preload_next) {
                #pragma unroll
                for (int r = 0; r < R; r++) {
                    int row = nrow0 + r;
                    if (row > NNODES - 1) row = NNODES - 1;
                    wvn[r] = Wb[(size_t)row * 256 + lane];
                }
            }
            float4 xv[B];
            #pragma unroll
            for (int b = 0; b < B; b++) xv[b] = xs[b * 256 + j * 64 + lane];
            #pragma unroll
            for (int r = 0; r < R; r++) {
                #pragma unroll
                for (int b = 0; b < B; b++) {
                    acc[r * 8 + b] += wv[r].x * xv[b].x + wv[r].y * xv[b].y +
                                      wv[r].z * xv[b].z + wv[r].w * xv[b].w;
                }
            }
            #pragma unroll
            for (int r = 0; r < R; r++) wv[r] = wvn[r];
        }
    };

#define FOLD_LEVEL(MASK, NOUT)                                   \
    _Pragma("unroll")                                            \
    for (int i = 0; i < (NOUT); i++) {                           \
        const float lo = acc[2 * i];                             \
        const float hi = acc[2 * i + 1];                         \
        const float send = (lane & (MASK)) ? lo : hi;            \
        const float keep = (lane & (MASK)) ? hi : lo;            \
        acc[i] = keep + __shfl_xor(send, (MASK), 64);            \
    }

    auto fold_store = [&](int prow0) {
        FOLD_LEVEL(1, 16)
        FOLD_LEVEL(2, 8)
        FOLD_LEVEL(4, 4)
        FOLD_LEVEL(8, 2)
        FOLD_LEVEL(16, 1)
        acc[0] += __shfl_xor(acc[0], 32, 64);  // combine halves
        if (lane < 32) {
            const int r = lane >> 3;
            const int b = lane & 7;
            const int row = prow0 + r;
            if (row < NNODES) {
                const float z = acc[0] + bias[row];
                sig[(size_t)row * B + b] = 1.f / (1.f + expf(-z));
            }
        }
    };

    run_pass(rowbase, true, rowbase + R);
    fold_store(rowbase);           // epilogue overlaps pass-1's in-flight loads
    run_pass(rowbase + R, false, 0);
    fold_store(rowbase + R);
#undef FOLD_LEVEL
}

// Kernel 2: out[b*T + t] = prod_{d} sig[paths[ids[b][t]][d] * B + b]
__global__ __launch_bounds__(256) void hsm_prod_kernel(
    const int* __restrict__ ids,    // [B][T]
    const int* __restrict__ paths,  // [V][D]
    const float* __restrict__ sig,  // [NNODES][B]
    float* __restrict__ out)        // [B][T]
{
    const int i = blockIdx.x * blockDim.x + threadIdx.x;
    if (i >= B * T) return;
    const int b = i / T;
    const int id = ids[i];
    const int* p = paths + (size_t)id * D;
    float prod = 1.f;
    #pragma unroll
    for (int d = 0; d < D; d++) {
        prod *= sig[(size_t)p[d] * B + b];
    }
    out[i] = prod;
}

extern "C" void kernel_launch(void* const* d_in, const int* in_sizes, int n_in,
                              void* d_out, int out_size, void* d_ws, size_t ws_size,
                              hipStream_t stream) {
    const float* x     = (const float*)d_in[0];  // [B, DM]
    const int*   ids   = (const int*)d_in[1];    // [B, T]
    const int*   paths = (const int*)d_in[2];    // [V, D]
    const float* W     = (const float*)d_in[3];  // [NNODES, DM]
    const float* bias  = (const float*)d_in[4];  // [NNODES]
    float* out = (float*)d_out;                  // [B, T]
    float* sig = (float*)d_ws;                   // [NNODES, B] = 1 MB scratch

    const int grid1 = (V + 31) / 32;  // 1024 blocks x 32 rows = 32768 >= NNODES
    hsm_logits_kernel<<<grid1, 256, 0, stream>>>(x, W, bias, sig);

    const int grid2 = (B * T + 255) / 256;  // 32
    hsm_prod_kernel<<<grid2, 256, 0, stream>>>(ids, paths, sig, out);
}

// Round 7
// 197.542 us; speedup vs baseline: 1.0552x; 1.0552x over previous
//
#include <hip/hip_runtime.h>
#include <math.h>

#define V 32768
#define D 15
#define DM 1024
#define B 8
#define T 1024
#define NNODES (V - 1)  // 32767
#define R 4             // rows per pass per wave; 2 passes -> 8 rows/wave, 32/block

// Native vector type: __builtin_nontemporal_load requires a pointer to a scalar
// or native vector type; HIP's float4 (HIP_vector_type struct) is rejected.
typedef float vfloat4 __attribute__((ext_vector_type(4)));

// Kernel 1: sig[v*B + b] = sigmoid(dot(W[v], x[b]) + bias[v]) for all internal nodes.
// Grid 1024 x 256 threads (4 waves). Each wave: 2 passes of R=4 rows, K split across
// 64 lanes (4 float4 per lane per row), one-iteration W prefetch.
//
// R5 theory under test: kernel time (~60 us) is invariant to inner-loop structure;
// hypothesis is dirty-L3 interference — the harness's 512 MB ws-poison fill leaves
// the 256 MB Infinity Cache full of dirty lines, and W-read allocations force
// concurrent writeback (~390 MB effective HBM traffic instead of 134 MB). W has
// zero reuse, so all W loads are NONTEMPORAL (no cache allocation).
// R3 lesson preserved: all acc[] indices are compile-time constants (no scratch).
__global__ __launch_bounds__(256, 4) void hsm_logits_kernel(
    const float* __restrict__ x,     // [B][DM]
    const float* __restrict__ W,     // [NNODES][DM]
    const float* __restrict__ bias,  // [NNODES]
    float* __restrict__ sig)         // [NNODES][B]
{
    __shared__ vfloat4 xs[B * DM / 4];  // 32 KB, xs[b*256 + u]

    const vfloat4* x4 = (const vfloat4*)x;
    #pragma unroll
    for (int i = threadIdx.x; i < B * DM / 4; i += 256) xs[i] = x4[i];
    __syncthreads();

    const int wave = __builtin_amdgcn_readfirstlane(threadIdx.x >> 6);  // scalarize
    const int lane = threadIdx.x & 63;
    const int rowbase = blockIdx.x * 32 + wave * 8;

    const vfloat4* Wb = (const vfloat4*)W;

    vfloat4 wv[R], wvn[R];
    float acc[R * B];  // acc[r*8+b]

    // Preload pass-0, j=0 (nontemporal: W lines are single-use).
    #pragma unroll
    for (int r = 0; r < R; r++) {
        int row = rowbase + r;
        if (row > NNODES - 1) row = NNODES - 1;  // scalar clamp; store guarded below
        wv[r] = __builtin_nontemporal_load(&Wb[(size_t)row * 256 + lane]);
    }

    auto run_pass = [&](int prow0, bool preload_next, int nrow0) {
        #pragma unroll
        for (int i = 0; i < R * B; i++) acc[i] = 0.f;
        #pragma unroll
        for (int j = 0; j < 4; j++) {
            if (j < 3) {
                #pragma unroll
                for (int r = 0; r < R; r++) {
                    int row = prow0 + r;
                    if (row > NNODES - 1) row = NNODES - 1;
                    wvn[r] = __builtin_nontemporal_load(
                        &Wb[(size_t)row * 256 + (j + 1) * 64 + lane]);
                }
            } else if (preload_next) {
                #pragma unroll
                for (int r = 0; r < R; r++) {
                    int row = nrow0 + r;
                    if (row > NNODES - 1) row = NNODES - 1;
                    wvn[r] = __builtin_nontemporal_load(
                        &Wb[(size_t)row * 256 + lane]);
                }
            }
            vfloat4 xv[B];
            #pragma unroll
            for (int b = 0; b < B; b++) xv[b] = xs[b * 256 + j * 64 + lane];
            #pragma unroll
            for (int r = 0; r < R; r++) {
                #pragma unroll
                for (int b = 0; b < B; b++) {
                    acc[r * 8 + b] += wv[r].x * xv[b].x + wv[r].y * xv[b].y +
                                      wv[r].z * xv[b].z + wv[r].w * xv[b].w;
                }
            }
            #pragma unroll
            for (int r = 0; r < R; r++) wv[r] = wvn[r];
        }
    };

#define FOLD_LEVEL(MASK, NOUT)                                   \
    _Pragma("unroll")                                            \
    for (int i = 0; i < (NOUT); i++) {                           \
        const float lo = acc[2 * i];                             \
        const float hi = acc[2 * i + 1];                         \
        const float send = (lane & (MASK)) ? lo : hi;            \
        const float keep = (lane & (MASK)) ? hi : lo;            \
        acc[i] = keep + __shfl_xor(send, (MASK), 64);            \
    }

    auto fold_store = [&](int prow0) {
        FOLD_LEVEL(1, 16)
        FOLD_LEVEL(2, 8)
        FOLD_LEVEL(4, 4)
        FOLD_LEVEL(8, 2)
        FOLD_LEVEL(16, 1)
        acc[0] += __shfl_xor(acc[0], 32, 64);  // combine halves
        if (lane < 32) {
            const int r = lane >> 3;
            const int b = lane & 7;
            const int row = prow0 + r;
            if (row < NNODES) {
                const float z = acc[0] + bias[row];
                sig[(size_t)row * B + b] = 1.f / (1.f + expf(-z));  // cached: k2 reads it
            }
        }
    };

    run_pass(rowbase, true, rowbase + R);
    fold_store(rowbase);           // epilogue overlaps pass-1's in-flight loads
    run_pass(rowbase + R, false, 0);
    fold_store(rowbase + R);
#undef FOLD_LEVEL
}

// Kernel 2: out[b*T + t] = prod_{d} sig[paths[ids[b][t]][d] * B + b]
__global__ __launch_bounds__(256) void hsm_prod_kernel(
    const int* __restrict__ ids,    // [B][T]
    const int* __restrict__ paths,  // [V][D]
    const float* __restrict__ sig,  // [NNODES][B]
    float* __restrict__ out)        // [B][T]
{
    const int i = blockIdx.x * blockDim.x + threadIdx.x;
    if (i >= B * T) return;
    const int b = i / T;
    const int id = ids[i];
    const int* p = paths + (size_t)id * D;
    // Vectorize the 60-byte path row: 3 x int4 + 3 scalars (int4 at offset 48
    // would read 4 B past the allocation for id == V-1).
    const int4* p4 = (const int4*)p;
    int4 n0 = p4[0], n1 = p4[1], n2 = p4[2];
    float prod = 1.f;
    prod *= sig[(size_t)n0.x * B + b] * sig[(size_t)n0.y * B + b] *
            sig[(size_t)n0.z * B + b] * sig[(size_t)n0.w * B + b];
    prod *= sig[(size_t)n1.x * B + b] * sig[(size_t)n1.y * B + b] *
            sig[(size_t)n1.z * B + b] * sig[(size_t)n1.w * B + b];
    prod *= sig[(size_t)n2.x * B + b] * sig[(size_t)n2.y * B + b] *
            sig[(size_t)n2.z * B + b] * sig[(size_t)n2.w * B + b];
    prod *= sig[(size_t)p[12] * B + b] * sig[(size_t)p[13] * B + b] *
            sig[(size_t)p[14] * B + b];
    out[i] = prod;
}

extern "C" void kernel_launch(void* const* d_in, const int* in_sizes, int n_in,
                              void* d_out, int out_size, void* d_ws, size_t ws_size,
                              hipStream_t stream) {
    const float* x     = (const float*)d_in[0];  // [B, DM]
    const int*   ids   = (const int*)d_in[1];    // [B, T]
    const int*   paths = (const int*)d_in[2];    // [V, D]
    const float* W     = (const float*)d_in[3];  // [NNODES, DM]
    const float* bias  = (const float*)d_in[4];  // [NNODES]
    float* out = (float*)d_out;                  // [B, T]
    float* sig = (float*)d_ws;                   // [NNODES, B] = 1 MB scratch

    const int grid1 = (V + 31) / 32;  // 1024 blocks x 32 rows = 32768 >= NNODES
    hsm_logits_kernel<<<grid1, 256, 0, stream>>>(x, W, bias, sig);

    const int grid2 = (B * T + 255) / 256;  // 32
    hsm_prod_kernel<<<grid2, 256, 0, stream>>>(ids, paths, sig, out);
}